// Round 11
// baseline (171.045 us; speedup 1.0000x reference)
//
#include <hip/hip_runtime.h>
#include <hip/hip_bf16.h>

#define D_MODEL   1024
#define D_STATE   128
#define D_INNER   2048
#define NHEADS    32
#define HEADDIM   64
#define D_IN_PROJ 4384   // 2*D_INNER + 2*D_STATE + NHEADS
#define NPROJ_PAD 4480   // GEMM tile padding; stores masked to 4384
#define CONV_DIM  2304   // D_INNER + 2*D_STATE
#define BATCH     2
#define SEQLEN    512
#define M_TOKENS  (BATCH*SEQLEN)   // 1024
#define EPS       1e-5f
#define LC        64               // SSD chunk length
#define NCH       (SEQLEN/LC)      // 8 chunks

typedef __bf16 bf16x8 __attribute__((ext_vector_type(8)));
typedef float  f32x4  __attribute__((ext_vector_type(4)));

__device__ __forceinline__ ushort f2bf(float f) {
  union { float f; unsigned int i; } v; v.f = f;
  unsigned int x = v.i;
  return (ushort)((x + 0x7fffu + ((x >> 16) & 1u)) >> 16);
}
__device__ __forceinline__ float bf2f(ushort u) {
  union { unsigned int i; float f; } v; v.i = ((unsigned int)u) << 16; return v.f;
}

__device__ __forceinline__ void gload_lds16u(const ushort* g, ushort* l) {
  __builtin_amdgcn_global_load_lds(
      (const __attribute__((address_space(1))) void*)g,
      (__attribute__((address_space(3))) void*)l, 16, 0, 0);
}

// ---------------------------------------------------------------------------
// fused fp32->bf16 conversion (u, W_in, W_out*norm_w) + zero-init of out and
// sumsq (absorbs the two hipMemsetAsync launches). 8 elems/thread.
// ---------------------------------------------------------------------------
__device__ __forceinline__ void cvt8(const float* __restrict__ s,
                                     ushort* __restrict__ d, int i) {
  const float4 a = *(const float4*)(s + i);
  const float4 b = *(const float4*)(s + i + 4);
  uint4 v;
  v.x = (unsigned)f2bf(a.x) | ((unsigned)f2bf(a.y) << 16);
  v.y = (unsigned)f2bf(a.z) | ((unsigned)f2bf(a.w) << 16);
  v.z = (unsigned)f2bf(b.x) | ((unsigned)f2bf(b.y) << 16);
  v.w = (unsigned)f2bf(b.z) | ((unsigned)f2bf(b.w) << 16);
  *(uint4*)(d + i) = v;
}
__global__ __launch_bounds__(256) void cvt3z(const float* __restrict__ s0, ushort* __restrict__ d0, int n0,
                                             const float* __restrict__ s1, ushort* __restrict__ d1, int n1,
                                             const float* __restrict__ s2, ushort* __restrict__ d2, int n2,
                                             const float* __restrict__ nw,
                                             float* __restrict__ zout, int n3,
                                             float* __restrict__ zsum, int n4) {
  const int i = (blockIdx.x * 256 + threadIdx.x) * 8;
  if (i < n0)           cvt8(s0, d0, i);
  else if (i < n0 + n1) cvt8(s1, d1, i - n0);
  else if (i < n0 + n1 + n2) {
    // W_out row-major [n][k], fold norm_w[k] (k = j % D_INNER, 8-aligned)
    const int j = i - n0 - n1;
    const int k = j & (D_INNER - 1);
    const float4 a = *(const float4*)(s2 + j);
    const float4 b = *(const float4*)(s2 + j + 4);
    const float4 wa = *(const float4*)(nw + k);
    const float4 wb = *(const float4*)(nw + k + 4);
    uint4 v;
    v.x = (unsigned)f2bf(a.x * wa.x) | ((unsigned)f2bf(a.y * wa.y) << 16);
    v.y = (unsigned)f2bf(a.z * wa.z) | ((unsigned)f2bf(a.w * wa.w) << 16);
    v.z = (unsigned)f2bf(b.x * wb.x) | ((unsigned)f2bf(b.y * wb.y) << 16);
    v.w = (unsigned)f2bf(b.z * wb.z) | ((unsigned)f2bf(b.w * wb.w) << 16);
    *(uint4*)(d2 + j) = v;
  } else if (i < n0 + n1 + n2 + n3) {
    const int j = i - n0 - n1 - n2;
    const float4 z = {0.f, 0.f, 0.f, 0.f};
    *(float4*)(zout + j) = z;
    *(float4*)(zout + j + 4) = z;
  } else if (i < n0 + n1 + n2 + n3 + n4) {
    const int j = i - n0 - n1 - n2 - n3;
    const float4 z = {0.f, 0.f, 0.f, 0.f};
    *(float4*)(zsum + j) = z;
    *(float4*)(zsum + j + 4) = z;
  }
}

// ---------------------------------------------------------------------------
// tiled GEMM, BK=32*PK LDS panels, single-buffered (round-8 form — measured
// best; explicit dbuf was neutral per m99/m100-style barrier-drain semantics).
// bf16 in, bf16 out (masked). 256 thr / 2x2 waves.
// ---------------------------------------------------------------------------
template <int BM, int BN, int PK>
__global__ __launch_bounds__(256) void gemm_tile(const ushort* __restrict__ A,
                                                 const ushort* __restrict__ Bt,
                                                 ushort* __restrict__ C,
                                                 int Nreal, int K, int ldc) {
  constexpr int WM = BM / 2, WN = BN / 2, FM = WM / 16, FN = WN / 16;
  constexpr int LA = BM * 4 / 256, LB = BN * 4 / 256;   // staging iters / panel
  __shared__ ushort As[PK * BM * 32];
  __shared__ ushort Bs[PK * BN * 32];
  const int tid = threadIdx.x, lane = tid & 63, wave = tid >> 6;
  const int r16 = lane & 15, q = lane >> 4;
  const int wm = wave & 1, wn = wave >> 1;
  const int m0 = blockIdx.y * BM, n0 = blockIdx.x * BN;

  f32x4 acc[FM][FN] = {};

  for (int k0 = 0; k0 < K; k0 += 32 * PK) {
    __syncthreads();
    #pragma unroll
    for (int pp = 0; pp < PK; ++pp) {
      #pragma unroll
      for (int it = 0; it < LA; ++it) {
        const int idx = it * 256 + tid;
        gload_lds16u(A + (size_t)(m0 + (idx >> 2)) * K + k0 + pp * 32 + (idx & 3) * 8,
                     As + pp * BM * 32 + (it * 256 + wave * 64) * 8);
      }
      #pragma unroll
      for (int it = 0; it < LB; ++it) {
        const int idx = it * 256 + tid;
        gload_lds16u(Bt + (size_t)(n0 + (idx >> 2)) * K + k0 + pp * 32 + (idx & 3) * 8,
                     Bs + pp * BN * 32 + (it * 256 + wave * 64) * 8);
      }
    }
    __syncthreads();

    #pragma unroll
    for (int pp = 0; pp < PK; ++pp) {
      bf16x8 af[FM], bfr[FN];
      #pragma unroll
      for (int i = 0; i < FM; ++i)
        af[i] = *(const bf16x8*)(const void*)(As + pp * BM * 32 + (wm * WM + i * 16 + r16) * 32 + q * 8);
      #pragma unroll
      for (int j = 0; j < FN; ++j)
        bfr[j] = *(const bf16x8*)(const void*)(Bs + pp * BN * 32 + (wn * WN + j * 16 + r16) * 32 + q * 8);
      #pragma unroll
      for (int i = 0; i < FM; ++i)
        #pragma unroll
        for (int j = 0; j < FN; ++j)
          acc[i][j] = __builtin_amdgcn_mfma_f32_16x16x32_bf16(af[i], bfr[j], acc[i][j], 0, 0, 0);
    }
  }

  #pragma unroll
  for (int i = 0; i < FM; ++i) {
    const int row = m0 + wm * WM + i * 16 + q * 4;
    #pragma unroll
    for (int j = 0; j < FN; ++j) {
      const int col = n0 + wn * WN + j * 16 + r16;
      if (col < Nreal) {
        #pragma unroll
        for (int r = 0; r < 4; ++r)
          C[(size_t)(row + r) * ldc + col] = f2bf(acc[i][j][r]);
      }
    }
  }
}

// ---------------------------------------------------------------------------
// out_proj split-K GEMM (BK=128, 4 panels, single-buffered) + fused RMS.
// epilogue: out += acc * rsqrt(sumsq[row]/D_INNER + eps) via unsafeAtomicAdd.
// ---------------------------------------------------------------------------
__global__ __launch_bounds__(256) void gemm_sk(const ushort* __restrict__ A,
                                               const ushort* __restrict__ Bt,
                                               float* __restrict__ C,
                                               const float* __restrict__ sumsq,
                                               int Khalf, int ldab, int ldc) {
  __shared__ ushort As[4 * 64 * 32];
  __shared__ ushort Bs[4 * 64 * 32];
  const int tid = threadIdx.x, lane = tid & 63, wave = tid >> 6;
  const int r16 = lane & 15, q = lane >> 4;
  const int wm = wave & 1, wn = wave >> 1;
  const int m0 = blockIdx.y * 64, n0 = blockIdx.x * 64;
  const int kb = blockIdx.z * Khalf;

  f32x4 acc[2][2] = {};
  for (int k0 = 0; k0 < Khalf; k0 += 128) {
    __syncthreads();
    #pragma unroll
    for (int pp = 0; pp < 4; ++pp) {
      gload_lds16u(A + (size_t)(m0 + (tid >> 2)) * ldab + kb + k0 + pp * 32 + (tid & 3) * 8,
                   As + pp * 64 * 32 + (tid & ~63) * 8);
      gload_lds16u(Bt + (size_t)(n0 + (tid >> 2)) * ldab + kb + k0 + pp * 32 + (tid & 3) * 8,
                   Bs + pp * 64 * 32 + (tid & ~63) * 8);
    }
    __syncthreads();

    #pragma unroll
    for (int pp = 0; pp < 4; ++pp) {
      bf16x8 af[2], bfr[2];
      #pragma unroll
      for (int i = 0; i < 2; ++i)
        af[i] = *(const bf16x8*)(const void*)(As + pp * 64 * 32 + (wm * 32 + i * 16 + r16) * 32 + q * 8);
      #pragma unroll
      for (int j = 0; j < 2; ++j)
        bfr[j] = *(const bf16x8*)(const void*)(Bs + pp * 64 * 32 + (wn * 32 + j * 16 + r16) * 32 + q * 8);
      #pragma unroll
      for (int i = 0; i < 2; ++i)
        #pragma unroll
        for (int j = 0; j < 2; ++j)
          acc[i][j] = __builtin_amdgcn_mfma_f32_16x16x32_bf16(af[i], bfr[j], acc[i][j], 0, 0, 0);
    }
  }

  #pragma unroll
  for (int i = 0; i < 2; ++i) {
    const int row = m0 + wm * 32 + i * 16 + q * 4;
    float rms[4];
    #pragma unroll
    for (int r = 0; r < 4; ++r)
      rms[r] = rsqrtf(sumsq[row + r] * (1.f / D_INNER) + EPS);
    #pragma unroll
    for (int j = 0; j < 2; ++j) {
      const int col = n0 + wn * 32 + j * 16 + r16;
      #pragma unroll
      for (int r = 0; r < 4; ++r)
        unsafeAtomicAdd(&C[(size_t)(row + r) * ldc + col], acc[i][j][r] * rms[r]);
    }
  }
}

// ---------------------------------------------------------------------------
// fused: [blocks 0..1151] causal depthwise conv (k=4) + SiLU over bf16 zx,
// bf16 out; [blocks 1152..1215] dt softplus + chunk-local prefix csum.
// ---------------------------------------------------------------------------
__global__ __launch_bounds__(256) void conv_dt(const ushort* __restrict__ zx,
                                               const float* __restrict__ cw,
                                               const float* __restrict__ cb,
                                               ushort* __restrict__ xbc,
                                               const float* __restrict__ dt_bias,
                                               const float* __restrict__ A_log,
                                               float* __restrict__ dts,
                                               float* __restrict__ csum) {
  const int blk = blockIdx.x;
  if (blk < 1152) {
    const int g  = blk / 9;                       // [0,128) t-group
    const int c  = (blk % 9) * 256 + threadIdx.x; // [0,2304)
    const int b  = g >> 6;
    const int t0 = (g & 63) * 8;
    const float4 w4 = *(const float4*)(cw + c * 4);
    const float bias = cb[c];
    const ushort* col = zx + (size_t)(b * SEQLEN) * D_IN_PROJ + D_INNER + c;
    float win[11];
    #pragma unroll
    for (int k = 0; k < 11; ++k) {
      const int t = t0 - 3 + k;
      win[k] = (t >= 0) ? bf2f(col[(size_t)t * D_IN_PROJ]) : 0.f;
    }
    #pragma unroll
    for (int i = 0; i < 8; ++i) {
      float a = bias;
      a = fmaf(win[i],     w4.x, a);
      a = fmaf(win[i + 1], w4.y, a);
      a = fmaf(win[i + 2], w4.z, a);
      a = fmaf(win[i + 3], w4.w, a);
      const float s = a / (1.f + __expf(-a));
      xbc[(size_t)(b * SEQLEN + t0 + i) * CONV_DIM + c] = f2bf(s);
    }
  } else {
    const int bh = blk - 1152;
    const int b = bh >> 5, h = bh & 31;
    const int wave = threadIdx.x >> 6, lane = threadIdx.x & 63;
    const float dtb = dt_bias[h];
    const float An  = -__expf(A_log[h]);
    for (int cc = wave; cc < NCH; cc += 4) {
      const int t = cc * LC + lane;
      const float raw = bf2f(zx[(size_t)(b * SEQLEN + t) * D_IN_PROJ + (D_INNER + CONV_DIM) + h]) + dtb;
      const float sp = (raw > 20.f) ? raw : log1pf(__expf(raw));
      float x = sp * An;
      #pragma unroll
      for (int off = 1; off < 64; off <<= 1) {
        const float v = __shfl_up(x, off);
        if (lane >= off) x += v;
      }
      dts[(size_t)bh * SEQLEN + t]  = sp;
      csum[(size_t)bh * SEQLEN + t] = x;
    }
  }
}

// ---------------------------------------------------------------------------
// K1 (fused G + intra). B/C/x read from bf16 xbc. dS now written TRANSPOSED
// as dS[p][n] (p<64, n<128), packing 4 consecutive-n accS values per uint2 —
// enables dwordx4 reads in chunk_inter's state rebuild.
// ---------------------------------------------------------------------------
__global__ __launch_bounds__(256) void chunk_intra(const ushort* __restrict__ xbc,
                                                   const float* __restrict__ dts,
                                                   const float* __restrict__ csum,
                                                   ushort* __restrict__ Yi,
                                                   ushort* __restrict__ dS) {
  const int blk = blockIdx.x;
  const int c = blk & 7, h = (blk >> 3) & 31, b = blk >> 8;
  const int bh = b * 32 + h;
  const int tid = threadIdx.x, lane = tid & 63, wave = tid >> 6;
  const int r16 = lane & 15, q = lane >> 4;

  __shared__ ushort Ml[64 * 72];
  __shared__ ushort Xt[64 * 72];
  __shared__ ushort Bw[128 * 72];
  __shared__ float dtl[LC], csl[LC];

  if (tid < LC) {
    dtl[tid] = dts[(size_t)bh * SEQLEN + c * LC + tid];
    csl[tid] = csum[(size_t)bh * SEQLEN + c * LC + tid];
  }
  __syncthreads();
  const float cs63 = csl[LC - 1];

  const ushort* rowbase = xbc + (size_t)(b * SEQLEN + c * LC) * CONV_DIM;
  const ushort* Cp = rowbase + (size_t)(wave * 16 + r16) * CONV_DIM + D_INNER + 128 + q * 8;
  const ushort* Bp = rowbase + (size_t)r16 * CONV_DIM + D_INNER + q * 8;
  f32x4 g[4] = {};
  #pragma unroll
  for (int kk = 0; kk < 4; ++kk) {
    const bf16x8 a = *(const bf16x8*)(const void*)(Cp + kk * 32);
    #pragma unroll
    for (int j = 0; j < 4; ++j) {
      const bf16x8 bb = *(const bf16x8*)(const void*)(Bp + (size_t)j * 16 * CONV_DIM + kk * 32);
      g[j] = __builtin_amdgcn_mfma_f32_16x16x32_bf16(a, bb, g[j], 0, 0, 0);
    }
  }
  float cst[4];
  #pragma unroll
  for (int r = 0; r < 4; ++r) cst[r] = csl[wave * 16 + q * 4 + r];
  #pragma unroll
  for (int j = 0; j < 4; ++j) {
    const int s = j * 16 + r16;
    const float ds_ = dtl[s], css = csl[s];
    #pragma unroll
    for (int r = 0; r < 4; ++r) {
      const int t = wave * 16 + q * 4 + r;
      const float v = (s <= t) ? g[j][r] * ds_ * __expf(cst[r] - css) : 0.f;
      Ml[t * 72 + s] = f2bf(v);
    }
  }

  const ushort* xb = rowbase + h * HEADDIM;
  #pragma unroll
  for (int i = 0; i < 16; ++i) {
    const int idx = i * 256 + tid;
    const int s = idx >> 6, p = idx & 63;
    Xt[p * 72 + s] = xb[(size_t)s * CONV_DIM + p];
  }
  const ushort* Bb = rowbase + D_INNER;
  #pragma unroll
  for (int i = 0; i < 32; ++i) {
    const int idx = i * 256 + tid;
    const int s = idx >> 7, n = idx & 127;
    const float w = dtl[s] * __expf(cs63 - csl[s]);
    Bw[n * 72 + s] = f2bf(bf2f(Bb[(size_t)s * CONV_DIM + n]) * w);
  }
  __syncthreads();

  f32x4 accY[4] = {};
  f32x4 accS[2][4] = {};
  #pragma unroll
  for (int kk = 0; kk < 2; ++kk) {
    const bf16x8 am = *(const bf16x8*)(const void*)(Ml + (wave * 16 + r16) * 72 + kk * 32 + q * 8);
    const bf16x8 a0 = *(const bf16x8*)(const void*)(Bw + (wave * 32 + r16) * 72 + kk * 32 + q * 8);
    const bf16x8 a1 = *(const bf16x8*)(const void*)(Bw + (wave * 32 + 16 + r16) * 72 + kk * 32 + q * 8);
    #pragma unroll
    for (int j = 0; j < 4; ++j) {
      const bf16x8 bx = *(const bf16x8*)(const void*)(Xt + (j * 16 + r16) * 72 + kk * 32 + q * 8);
      accY[j]    = __builtin_amdgcn_mfma_f32_16x16x32_bf16(am, bx, accY[j], 0, 0, 0);
      accS[0][j] = __builtin_amdgcn_mfma_f32_16x16x32_bf16(a0, bx, accS[0][j], 0, 0, 0);
      accS[1][j] = __builtin_amdgcn_mfma_f32_16x16x32_bf16(a1, bx, accS[1][j], 0, 0, 0);
    }
  }

  ushort* Yp = Yi + (size_t)blk * 4096;
  #pragma unroll
  for (int j = 0; j < 4; ++j)
    #pragma unroll
    for (int r = 0; r < 4; ++r)
      Yp[(wave * 16 + q * 4 + r) * 64 + j * 16 + r16] = f2bf(accY[j][r]);

  // transposed dS[p][n]: accS C-layout n = wave*32+u*16+q*4+r, p = j*16+r16;
  // 4 r-values are consecutive n -> pack into one 8 B store.
  ushort* Sp = dS + (size_t)blk * 8192;
  #pragma unroll
  for (int u = 0; u < 2; ++u)
    #pragma unroll
    for (int j = 0; j < 4; ++j) {
      const int p  = j * 16 + r16;
      const int nb = wave * 32 + u * 16 + q * 4;
      uint2 v;
      v.x = (unsigned)f2bf(accS[u][j][0]) | ((unsigned)f2bf(accS[u][j][1]) << 16);
      v.y = (unsigned)f2bf(accS[u][j][2]) | ((unsigned)f2bf(accS[u][j][3]) << 16);
      *(uint2*)(Sp + (size_t)p * 128 + nb) = v;
    }
}

// ---------------------------------------------------------------------------
// K3: rebuild start-state from transposed dS[p][n] (dwordx4 reads, closed-form
// decay), C·St via MFMA, add Yi + D*x, gate silu(z), write yn bf16 + atomic
// per-row sum(yg^2).
// ---------------------------------------------------------------------------
__global__ __launch_bounds__(256) void chunk_inter(const ushort* __restrict__ xbc,
                                                   const ushort* __restrict__ dS,
                                                   const ushort* __restrict__ Yi,
                                                   const ushort* __restrict__ zx,
                                                   const float* __restrict__ csum,
                                                   const float* __restrict__ Dp,
                                                   ushort* __restrict__ yn,
                                                   float* __restrict__ sumsq) {
  const int blk = blockIdx.x;
  const int c = blk & 7, h = (blk >> 3) & 31, b = blk >> 8;
  const int bh = b * 32 + h;
  const int tid = threadIdx.x, lane = tid & 63, wave = tid >> 6;
  const int r16 = lane & 15, q = lane >> 4;

  __shared__ ushort Stile[64 * 132];   // [p][n], pad 132

  const int p  = tid & 63;
  const int n0 = (tid >> 6) * 32;
  float S[32] = {};
  float w = 1.f;
  for (int cp = c - 1; cp >= 0; --cp) {
    const ushort* dp = dS + ((size_t)bh * 8 + cp) * 8192 + (size_t)p * 128 + n0;
    union { uint4 v[4]; ushort us[32]; } ld;
    ld.v[0] = *(const uint4*)(dp);
    ld.v[1] = *(const uint4*)(dp + 8);
    ld.v[2] = *(const uint4*)(dp + 16);
    ld.v[3] = *(const uint4*)(dp + 24);
    #pragma unroll
    for (int j = 0; j < 32; ++j)
      S[j] = fmaf(w, bf2f(ld.us[j]), S[j]);
    w *= __expf(csum[(size_t)bh * SEQLEN + cp * LC + (LC - 1)]);
  }
  #pragma unroll
  for (int j = 0; j < 16; ++j) {
    const unsigned v = (unsigned)f2bf(S[2 * j]) | ((unsigned)f2bf(S[2 * j + 1]) << 16);
    *(unsigned*)&Stile[p * 132 + n0 + 2 * j] = v;
  }
  __syncthreads();

  const ushort* rowbase = xbc + (size_t)(b * SEQLEN + c * LC) * CONV_DIM;
  const ushort* Cp = rowbase + (size_t)(wave * 16 + r16) * CONV_DIM + D_INNER + 128 + q * 8;
  f32x4 acc[4] = {};
  #pragma unroll
  for (int kk = 0; kk < 4; ++kk) {
    const bf16x8 a = *(const bf16x8*)(const void*)(Cp + kk * 32);
    #pragma unroll
    for (int j = 0; j < 4; ++j) {
      const bf16x8 bb = *(const bf16x8*)(const void*)(Stile + (j * 16 + r16) * 132 + kk * 32 + q * 8);
      acc[j] = __builtin_amdgcn_mfma_f32_16x16x32_bf16(a, bb, acc[j], 0, 0, 0);
    }
  }

  const float Dh = Dp[h];
  const ushort* Yp = Yi + (size_t)blk * 4096;
  float sc[4], ssq[4] = {0.f, 0.f, 0.f, 0.f};
  #pragma unroll
  for (int r = 0; r < 4; ++r)
    sc[r] = __expf(csum[(size_t)bh * SEQLEN + c * LC + wave * 16 + q * 4 + r]);
  #pragma unroll
  for (int j = 0; j < 4; ++j) {
    const int col = j * 16 + r16;
    #pragma unroll
    for (int r = 0; r < 4; ++r) {
      const int t = wave * 16 + q * 4 + r;
      const size_t row = (size_t)(b * SEQLEN + c * LC + t);
      const float xv = bf2f(xbc[row * CONV_DIM + h * HEADDIM + col]);
      const float yv = acc[j][r] * sc[r] + bf2f(Yp[t * 64 + col]) + Dh * xv;
      const float z  = bf2f(zx[row * D_IN_PROJ + h * HEADDIM + col]);
      const float yg = yv * (z / (1.f + __expf(-z)));
      yn[row * D_INNER + h * HEADDIM + col] = f2bf(yg);
      ssq[r] = fmaf(yg, yg, ssq[r]);
    }
  }
  #pragma unroll
  for (int o = 1; o < 16; o <<= 1) {
    #pragma unroll
    for (int r = 0; r < 4; ++r) ssq[r] += __shfl_xor(ssq[r], o);
  }
  if (r16 == 0) {
    #pragma unroll
    for (int r = 0; r < 4; ++r) {
      const int t = wave * 16 + q * 4 + r;
      unsafeAtomicAdd(&sumsq[b * SEQLEN + c * LC + t], ssq[r]);
    }
  }
}

// ---------------------------------------------------------------------------
extern "C" void kernel_launch(void* const* d_in, const int* in_sizes, int n_in,
                              void* d_out, int out_size, void* d_ws, size_t ws_size,
                              hipStream_t stream) {
  const float* u       = (const float*)d_in[0];
  const float* W_in    = (const float*)d_in[1];
  const float* conv_w  = (const float*)d_in[2];
  const float* conv_b  = (const float*)d_in[3];
  const float* dt_bias = (const float*)d_in[4];
  const float* A_log   = (const float*)d_in[5];
  const float* D_par   = (const float*)d_in[6];
  const float* norm_w  = (const float*)d_in[7];
  const float* W_out   = (const float*)d_in[8];
  float* out = (float*)d_out;

  char* ws = (char*)d_ws;
  // ws layout (bytes), 16B-aligned:
  //   zx_bf   bf16 [1024][4384]       8,978,432  @ 0
  //   xbc_bf  bf16 [1024][2304]       4,718,592  @ 8,978,432
  //   sumsq   fp32 [1024]                 4,096  @ 13,697,024
  //   yn      bf16 [1024][2048]       4,194,304  @ 13,701,120
  //   u_bf    bf16 [1024][1024]       2,097,152  @ 17,895,424   (dead after in_proj)
  //   Win_bf  bf16 [4384][1024]       8,978,432  @ 19,992,576   (dead after in_proj)
  //   Yi      bf16 [512][64][64]      4,194,304  @ 17,895,424   ALIAS u_bf+Win_bf
  //   Wout_bf bf16 [1024][2048]       4,194,304  @ 28,971,008
  //   dts     fp32 [64][512]            131,072  @ 33,165,312
  //   csum    fp32 [64][512]            131,072  @ 33,296,384
  //   dS      bf16 [512][64][128]     8,388,608  @ 33,427,456   (end 41,816,064)
  // in_proj reads Bt rows to 4480 -> 196,608 B past Win_bf into Wout_bf region
  // (finite bf16, written by cvt3z beforehand; results masked on store).
  ushort* zx      = (ushort*)ws;
  ushort* xbc     = (ushort*)(ws + 8978432);
  float*  sumsq   = (float*)(ws + 13697024);
  ushort* yn      = (ushort*)(ws + 13701120);
  ushort* u_bf    = (ushort*)(ws + 17895424);
  ushort* Win_bf  = (ushort*)(ws + 19992576);
  ushort* Yi      = (ushort*)(ws + 17895424);
  ushort* Wout_bf = (ushort*)(ws + 28971008);
  float*  dts     = (float*)(ws + 33165312);
  float*  csum    = (float*)(ws + 33296384);
  ushort* dS      = (ushort*)(ws + 33427456);

  const int n_u = M_TOKENS * D_MODEL, n_wi = D_IN_PROJ * D_MODEL, n_wo = D_MODEL * D_INNER;
  const int n_out = M_TOKENS * D_MODEL, n_ss = M_TOKENS;
  const int n_tot = n_u + n_wi + n_wo + n_out + n_ss;
  cvt3z<<<(n_tot + 2047) / 2048, 256, 0, stream>>>(
      u, u_bf, n_u, W_in, Win_bf, n_wi, W_out, Wout_bf, n_wo, norm_w,
      out, n_out, sumsq, n_ss);

  // in_proj: M=1024, N=4384 (grid padded to 4480), K=1024 — 560 blocks, BK=128
  gemm_tile<128, 64, 4><<<dim3(NPROJ_PAD / 64, M_TOKENS / 128), 256, 0, stream>>>(
      u_bf, Win_bf, zx, D_IN_PROJ, D_MODEL, D_IN_PROJ);
  // conv+silu (1152 blocks) and dt/csum (64 blocks) fused
  conv_dt<<<1152 + 64, 256, 0, stream>>>(zx, conv_w, conv_b, xbc,
                                         dt_bias, A_log, dts, csum);

  chunk_intra<<<BATCH * NHEADS * NCH, 256, 0, stream>>>(xbc, dts, csum, Yi, dS);
  chunk_inter<<<BATCH * NHEADS * NCH, 256, 0, stream>>>(xbc, dS, Yi, zx,
                                                        csum, D_par, yn, sumsq);

  // out_proj: M=1024, N=1024, K=2048 split 2x1024 — 512 blocks, rms in epilogue
  gemm_sk<<<dim3(D_MODEL / 64, M_TOKENS / 64, 2), 256, 0, stream>>>(
      yn, Wout_bf, out, sumsq, D_INNER / 2, D_INNER, D_MODEL);
}

// Round 12
// 164.120 us; speedup vs baseline: 1.0422x; 1.0422x over previous
//
#include <hip/hip_runtime.h>
#include <hip/hip_bf16.h>

#define D_MODEL   1024
#define D_STATE   128
#define D_INNER   2048
#define NHEADS    32
#define HEADDIM   64
#define D_IN_PROJ 4384   // 2*D_INNER + 2*D_STATE + NHEADS
#define NPROJ_PAD 4480   // GEMM tile padding; stores masked to 4384
#define CONV_DIM  2304   // D_INNER + 2*D_STATE
#define BATCH     2
#define SEQLEN    512
#define M_TOKENS  (BATCH*SEQLEN)   // 1024
#define EPS       1e-5f
#define LC        64               // SSD chunk length
#define NCH       (SEQLEN/LC)      // 8 chunks

typedef __bf16 bf16x8 __attribute__((ext_vector_type(8)));
typedef float  f32x4  __attribute__((ext_vector_type(4)));

__device__ __forceinline__ ushort f2bf(float f) {
  union { float f; unsigned int i; } v; v.f = f;
  unsigned int x = v.i;
  return (ushort)((x + 0x7fffu + ((x >> 16) & 1u)) >> 16);
}
__device__ __forceinline__ float bf2f(ushort u) {
  union { unsigned int i; float f; } v; v.i = ((unsigned int)u) << 16; return v.f;
}

__device__ __forceinline__ void gload_lds16u(const ushort* g, ushort* l) {
  __builtin_amdgcn_global_load_lds(
      (const __attribute__((address_space(1))) void*)g,
      (__attribute__((address_space(3))) void*)l, 16, 0, 0);
}

// ---------------------------------------------------------------------------
// fused fp32->bf16 conversion (u, W_in, W_out*norm_w) + zero-init of out and
// sumsq (absorbs the two hipMemsetAsync launches). 8 elems/thread.
// ---------------------------------------------------------------------------
__device__ __forceinline__ void cvt8(const float* __restrict__ s,
                                     ushort* __restrict__ d, int i) {
  const float4 a = *(const float4*)(s + i);
  const float4 b = *(const float4*)(s + i + 4);
  uint4 v;
  v.x = (unsigned)f2bf(a.x) | ((unsigned)f2bf(a.y) << 16);
  v.y = (unsigned)f2bf(a.z) | ((unsigned)f2bf(a.w) << 16);
  v.z = (unsigned)f2bf(b.x) | ((unsigned)f2bf(b.y) << 16);
  v.w = (unsigned)f2bf(b.z) | ((unsigned)f2bf(b.w) << 16);
  *(uint4*)(d + i) = v;
}
__global__ __launch_bounds__(256) void cvt3z(const float* __restrict__ s0, ushort* __restrict__ d0, int n0,
                                             const float* __restrict__ s1, ushort* __restrict__ d1, int n1,
                                             const float* __restrict__ s2, ushort* __restrict__ d2, int n2,
                                             const float* __restrict__ nw,
                                             float* __restrict__ zout, int n3,
                                             float* __restrict__ zsum, int n4) {
  const int i = (blockIdx.x * 256 + threadIdx.x) * 8;
  if (i < n0)           cvt8(s0, d0, i);
  else if (i < n0 + n1) cvt8(s1, d1, i - n0);
  else if (i < n0 + n1 + n2) {
    // W_out row-major [n][k], fold norm_w[k] (k = j % D_INNER, 8-aligned)
    const int j = i - n0 - n1;
    const int k = j & (D_INNER - 1);
    const float4 a = *(const float4*)(s2 + j);
    const float4 b = *(const float4*)(s2 + j + 4);
    const float4 wa = *(const float4*)(nw + k);
    const float4 wb = *(const float4*)(nw + k + 4);
    uint4 v;
    v.x = (unsigned)f2bf(a.x * wa.x) | ((unsigned)f2bf(a.y * wa.y) << 16);
    v.y = (unsigned)f2bf(a.z * wa.z) | ((unsigned)f2bf(a.w * wa.w) << 16);
    v.z = (unsigned)f2bf(b.x * wb.x) | ((unsigned)f2bf(b.y * wb.y) << 16);
    v.w = (unsigned)f2bf(b.z * wb.z) | ((unsigned)f2bf(b.w * wb.w) << 16);
    *(uint4*)(d2 + j) = v;
  } else if (i < n0 + n1 + n2 + n3) {
    const int j = i - n0 - n1 - n2;
    const float4 z = {0.f, 0.f, 0.f, 0.f};
    *(float4*)(zout + j) = z;
    *(float4*)(zout + j + 4) = z;
  } else if (i < n0 + n1 + n2 + n3 + n4) {
    const int j = i - n0 - n1 - n2 - n3;
    const float4 z = {0.f, 0.f, 0.f, 0.f};
    *(float4*)(zsum + j) = z;
    *(float4*)(zsum + j + 4) = z;
  }
}

// ---------------------------------------------------------------------------
// tiled GEMM, BK=32*PK LDS panels (global_load_lds contiguous dest preserved
// per panel). bf16 in, bf16 out (masked). 256 thr / 2x2 waves.
// Single-buffered: explicit dbuf measured neutral (m99/m100 semantics).
// ---------------------------------------------------------------------------
template <int BM, int BN, int PK>
__global__ __launch_bounds__(256) void gemm_tile(const ushort* __restrict__ A,
                                                 const ushort* __restrict__ Bt,
                                                 ushort* __restrict__ C,
                                                 int Nreal, int K, int ldc) {
  constexpr int WM = BM / 2, WN = BN / 2, FM = WM / 16, FN = WN / 16;
  constexpr int LA = BM * 4 / 256, LB = BN * 4 / 256;   // staging iters / panel
  __shared__ ushort As[PK * BM * 32];
  __shared__ ushort Bs[PK * BN * 32];
  const int tid = threadIdx.x, lane = tid & 63, wave = tid >> 6;
  const int r16 = lane & 15, q = lane >> 4;
  const int wm = wave & 1, wn = wave >> 1;
  const int m0 = blockIdx.y * BM, n0 = blockIdx.x * BN;

  f32x4 acc[FM][FN] = {};

  for (int k0 = 0; k0 < K; k0 += 32 * PK) {
    __syncthreads();
    #pragma unroll
    for (int pp = 0; pp < PK; ++pp) {
      #pragma unroll
      for (int it = 0; it < LA; ++it) {
        const int idx = it * 256 + tid;
        gload_lds16u(A + (size_t)(m0 + (idx >> 2)) * K + k0 + pp * 32 + (idx & 3) * 8,
                     As + pp * BM * 32 + (it * 256 + wave * 64) * 8);
      }
      #pragma unroll
      for (int it = 0; it < LB; ++it) {
        const int idx = it * 256 + tid;
        gload_lds16u(Bt + (size_t)(n0 + (idx >> 2)) * K + k0 + pp * 32 + (idx & 3) * 8,
                     Bs + pp * BN * 32 + (it * 256 + wave * 64) * 8);
      }
    }
    __syncthreads();

    #pragma unroll
    for (int pp = 0; pp < PK; ++pp) {
      bf16x8 af[FM], bfr[FN];
      #pragma unroll
      for (int i = 0; i < FM; ++i)
        af[i] = *(const bf16x8*)(const void*)(As + pp * BM * 32 + (wm * WM + i * 16 + r16) * 32 + q * 8);
      #pragma unroll
      for (int j = 0; j < FN; ++j)
        bfr[j] = *(const bf16x8*)(const void*)(Bs + pp * BN * 32 + (wn * WN + j * 16 + r16) * 32 + q * 8);
      #pragma unroll
      for (int i = 0; i < FM; ++i)
        #pragma unroll
        for (int j = 0; j < FN; ++j)
          acc[i][j] = __builtin_amdgcn_mfma_f32_16x16x32_bf16(af[i], bfr[j], acc[i][j], 0, 0, 0);
    }
  }

  #pragma unroll
  for (int i = 0; i < FM; ++i) {
    const int row = m0 + wm * WM + i * 16 + q * 4;
    #pragma unroll
    for (int j = 0; j < FN; ++j) {
      const int col = n0 + wn * WN + j * 16 + r16;
      if (col < Nreal) {
        #pragma unroll
        for (int r = 0; r < 4; ++r)
          C[(size_t)(row + r) * ldc + col] = f2bf(acc[i][j][r]);
      }
    }
  }
}

// ---------------------------------------------------------------------------
// out_proj split-K GEMM (BK=128, 4 panels) + fused RMS scaling.
// epilogue: out += acc * rsqrt(sumsq[row]/D_INNER + eps) via unsafeAtomicAdd.
// ---------------------------------------------------------------------------
__global__ __launch_bounds__(256) void gemm_sk(const ushort* __restrict__ A,
                                               const ushort* __restrict__ Bt,
                                               float* __restrict__ C,
                                               const float* __restrict__ sumsq,
                                               int Khalf, int ldab, int ldc) {
  __shared__ ushort As[4 * 64 * 32];
  __shared__ ushort Bs[4 * 64 * 32];
  const int tid = threadIdx.x, lane = tid & 63, wave = tid >> 6;
  const int r16 = lane & 15, q = lane >> 4;
  const int wm = wave & 1, wn = wave >> 1;
  const int m0 = blockIdx.y * 64, n0 = blockIdx.x * 64;
  const int kb = blockIdx.z * Khalf;

  f32x4 acc[2][2] = {};
  for (int k0 = 0; k0 < Khalf; k0 += 128) {
    __syncthreads();
    #pragma unroll
    for (int pp = 0; pp < 4; ++pp) {
      gload_lds16u(A + (size_t)(m0 + (tid >> 2)) * ldab + kb + k0 + pp * 32 + (tid & 3) * 8,
                   As + pp * 64 * 32 + (tid & ~63) * 8);
      gload_lds16u(Bt + (size_t)(n0 + (tid >> 2)) * ldab + kb + k0 + pp * 32 + (tid & 3) * 8,
                   Bs + pp * 64 * 32 + (tid & ~63) * 8);
    }
    __syncthreads();

    #pragma unroll
    for (int pp = 0; pp < 4; ++pp) {
      bf16x8 af[2], bfr[2];
      #pragma unroll
      for (int i = 0; i < 2; ++i)
        af[i] = *(const bf16x8*)(const void*)(As + pp * 64 * 32 + (wm * 32 + i * 16 + r16) * 32 + q * 8);
      #pragma unroll
      for (int j = 0; j < 2; ++j)
        bfr[j] = *(const bf16x8*)(const void*)(Bs + pp * 64 * 32 + (wn * 32 + j * 16 + r16) * 32 + q * 8);
      #pragma unroll
      for (int i = 0; i < 2; ++i)
        #pragma unroll
        for (int j = 0; j < 2; ++j)
          acc[i][j] = __builtin_amdgcn_mfma_f32_16x16x32_bf16(af[i], bfr[j], acc[i][j], 0, 0, 0);
    }
  }

  #pragma unroll
  for (int i = 0; i < 2; ++i) {
    const int row = m0 + wm * 32 + i * 16 + q * 4;
    float rms[4];
    #pragma unroll
    for (int r = 0; r < 4; ++r)
      rms[r] = rsqrtf(sumsq[row + r] * (1.f / D_INNER) + EPS);
    #pragma unroll
    for (int j = 0; j < 2; ++j) {
      const int col = n0 + wn * 32 + j * 16 + r16;
      #pragma unroll
      for (int r = 0; r < 4; ++r)
        unsafeAtomicAdd(&C[(size_t)(row + r) * ldc + col], acc[i][j][r] * rms[r]);
    }
  }
}

// ---------------------------------------------------------------------------
// fused: [blocks 0..1151] causal depthwise conv (k=4) + SiLU over bf16 zx,
// bf16 out; [blocks 1152..1215] dt softplus + chunk-local prefix csum.
// ---------------------------------------------------------------------------
__global__ __launch_bounds__(256) void conv_dt(const ushort* __restrict__ zx,
                                               const float* __restrict__ cw,
                                               const float* __restrict__ cb,
                                               ushort* __restrict__ xbc,
                                               const float* __restrict__ dt_bias,
                                               const float* __restrict__ A_log,
                                               float* __restrict__ dts,
                                               float* __restrict__ csum) {
  const int blk = blockIdx.x;
  if (blk < 1152) {
    const int g  = blk / 9;                       // [0,128) t-group
    const int c  = (blk % 9) * 256 + threadIdx.x; // [0,2304)
    const int b  = g >> 6;
    const int t0 = (g & 63) * 8;
    const float4 w4 = *(const float4*)(cw + c * 4);
    const float bias = cb[c];
    const ushort* col = zx + (size_t)(b * SEQLEN) * D_IN_PROJ + D_INNER + c;
    float win[11];
    #pragma unroll
    for (int k = 0; k < 11; ++k) {
      const int t = t0 - 3 + k;
      win[k] = (t >= 0) ? bf2f(col[(size_t)t * D_IN_PROJ]) : 0.f;
    }
    #pragma unroll
    for (int i = 0; i < 8; ++i) {
      float a = bias;
      a = fmaf(win[i],     w4.x, a);
      a = fmaf(win[i + 1], w4.y, a);
      a = fmaf(win[i + 2], w4.z, a);
      a = fmaf(win[i + 3], w4.w, a);
      const float s = a / (1.f + __expf(-a));
      xbc[(size_t)(b * SEQLEN + t0 + i) * CONV_DIM + c] = f2bf(s);
    }
  } else {
    const int bh = blk - 1152;
    const int b = bh >> 5, h = bh & 31;
    const int wave = threadIdx.x >> 6, lane = threadIdx.x & 63;
    const float dtb = dt_bias[h];
    const float An  = -__expf(A_log[h]);
    for (int cc = wave; cc < NCH; cc += 4) {
      const int t = cc * LC + lane;
      const float raw = bf2f(zx[(size_t)(b * SEQLEN + t) * D_IN_PROJ + (D_INNER + CONV_DIM) + h]) + dtb;
      const float sp = (raw > 20.f) ? raw : log1pf(__expf(raw));
      float x = sp * An;
      #pragma unroll
      for (int off = 1; off < 64; off <<= 1) {
        const float v = __shfl_up(x, off);
        if (lane >= off) x += v;
      }
      dts[(size_t)bh * SEQLEN + t]  = sp;
      csum[(size_t)bh * SEQLEN + t] = x;
    }
  }
}

// ---------------------------------------------------------------------------
// K1 (fused G + intra). B/C/x all read from bf16 xbc (B at +2048, C at +2176).
// ---------------------------------------------------------------------------
__global__ __launch_bounds__(256) void chunk_intra(const ushort* __restrict__ xbc,
                                                   const float* __restrict__ dts,
                                                   const float* __restrict__ csum,
                                                   ushort* __restrict__ Yi,
                                                   ushort* __restrict__ dS) {
  const int blk = blockIdx.x;
  const int c = blk & 7, h = (blk >> 3) & 31, b = blk >> 8;
  const int bh = b * 32 + h;
  const int tid = threadIdx.x, lane = tid & 63, wave = tid >> 6;
  const int r16 = lane & 15, q = lane >> 4;

  __shared__ ushort Ml[64 * 72];
  __shared__ ushort Xt[64 * 72];
  __shared__ ushort Bw[128 * 72];
  __shared__ float dtl[LC], csl[LC];

  if (tid < LC) {
    dtl[tid] = dts[(size_t)bh * SEQLEN + c * LC + tid];
    csl[tid] = csum[(size_t)bh * SEQLEN + c * LC + tid];
  }
  __syncthreads();
  const float cs63 = csl[LC - 1];

  const ushort* rowbase = xbc + (size_t)(b * SEQLEN + c * LC) * CONV_DIM;
  const ushort* Cp = rowbase + (size_t)(wave * 16 + r16) * CONV_DIM + D_INNER + 128 + q * 8;
  const ushort* Bp = rowbase + (size_t)r16 * CONV_DIM + D_INNER + q * 8;
  f32x4 g[4] = {};
  #pragma unroll
  for (int kk = 0; kk < 4; ++kk) {
    const bf16x8 a = *(const bf16x8*)(const void*)(Cp + kk * 32);
    #pragma unroll
    for (int j = 0; j < 4; ++j) {
      const bf16x8 bb = *(const bf16x8*)(const void*)(Bp + (size_t)j * 16 * CONV_DIM + kk * 32);
      g[j] = __builtin_amdgcn_mfma_f32_16x16x32_bf16(a, bb, g[j], 0, 0, 0);
    }
  }
  float cst[4];
  #pragma unroll
  for (int r = 0; r < 4; ++r) cst[r] = csl[wave * 16 + q * 4 + r];
  #pragma unroll
  for (int j = 0; j < 4; ++j) {
    const int s = j * 16 + r16;
    const float ds_ = dtl[s], css = csl[s];
    #pragma unroll
    for (int r = 0; r < 4; ++r) {
      const int t = wave * 16 + q * 4 + r;
      const float v = (s <= t) ? g[j][r] * ds_ * __expf(cst[r] - css) : 0.f;
      Ml[t * 72 + s] = f2bf(v);
    }
  }

  const ushort* xb = rowbase + h * HEADDIM;
  #pragma unroll
  for (int i = 0; i < 16; ++i) {
    const int idx = i * 256 + tid;
    const int s = idx >> 6, p = idx & 63;
    Xt[p * 72 + s] = xb[(size_t)s * CONV_DIM + p];
  }
  const ushort* Bb = rowbase + D_INNER;
  #pragma unroll
  for (int i = 0; i < 32; ++i) {
    const int idx = i * 256 + tid;
    const int s = idx >> 7, n = idx & 127;
    const float w = dtl[s] * __expf(cs63 - csl[s]);
    Bw[n * 72 + s] = f2bf(bf2f(Bb[(size_t)s * CONV_DIM + n]) * w);
  }
  __syncthreads();

  f32x4 accY[4] = {};
  f32x4 accS[2][4] = {};
  #pragma unroll
  for (int kk = 0; kk < 2; ++kk) {
    const bf16x8 am = *(const bf16x8*)(const void*)(Ml + (wave * 16 + r16) * 72 + kk * 32 + q * 8);
    const bf16x8 a0 = *(const bf16x8*)(const void*)(Bw + (wave * 32 + r16) * 72 + kk * 32 + q * 8);
    const bf16x8 a1 = *(const bf16x8*)(const void*)(Bw + (wave * 32 + 16 + r16) * 72 + kk * 32 + q * 8);
    #pragma unroll
    for (int j = 0; j < 4; ++j) {
      const bf16x8 bx = *(const bf16x8*)(const void*)(Xt + (j * 16 + r16) * 72 + kk * 32 + q * 8);
      accY[j]    = __builtin_amdgcn_mfma_f32_16x16x32_bf16(am, bx, accY[j], 0, 0, 0);
      accS[0][j] = __builtin_amdgcn_mfma_f32_16x16x32_bf16(a0, bx, accS[0][j], 0, 0, 0);
      accS[1][j] = __builtin_amdgcn_mfma_f32_16x16x32_bf16(a1, bx, accS[1][j], 0, 0, 0);
    }
  }

  ushort* Yp = Yi + (size_t)blk * 4096;
  #pragma unroll
  for (int j = 0; j < 4; ++j)
    #pragma unroll
    for (int r = 0; r < 4; ++r)
      Yp[(wave * 16 + q * 4 + r) * 64 + j * 16 + r16] = f2bf(accY[j][r]);

  ushort* Sp = dS + (size_t)blk * 8192;
  #pragma unroll
  for (int u = 0; u < 2; ++u)
    #pragma unroll
    for (int j = 0; j < 4; ++j)
      #pragma unroll
      for (int r = 0; r < 4; ++r)
        Sp[(wave * 32 + u * 16 + q * 4 + r) * 64 + j * 16 + r16] = f2bf(accS[u][j][r]);
}

// ---------------------------------------------------------------------------
// K3: rebuild start-state from dS (closed-form decay), C·St via MFMA,
// add Yi + D*x, gate silu(z), write yn bf16 + atomic per-row sum(yg^2).
// ---------------------------------------------------------------------------
__global__ __launch_bounds__(256) void chunk_inter(const ushort* __restrict__ xbc,
                                                   const ushort* __restrict__ dS,
                                                   const ushort* __restrict__ Yi,
                                                   const ushort* __restrict__ zx,
                                                   const float* __restrict__ csum,
                                                   const float* __restrict__ Dp,
                                                   ushort* __restrict__ yn,
                                                   float* __restrict__ sumsq) {
  const int blk = blockIdx.x;
  const int c = blk & 7, h = (blk >> 3) & 31, b = blk >> 8;
  const int bh = b * 32 + h;
  const int tid = threadIdx.x, lane = tid & 63, wave = tid >> 6;
  const int r16 = lane & 15, q = lane >> 4;

  __shared__ ushort Stile[64 * 132];   // [p][n], pad 132

  const int p  = tid & 63;
  const int n0 = (tid >> 6) * 32;
  float S[32] = {};
  float w = 1.f;
  for (int cp = c - 1; cp >= 0; --cp) {
    const ushort* dp = dS + ((size_t)bh * 8 + cp) * 8192 + (size_t)n0 * 64 + p;
    #pragma unroll
    for (int j = 0; j < 32; ++j)
      S[j] = fmaf(w, bf2f(dp[(size_t)j * 64]), S[j]);
    w *= __expf(csum[(size_t)bh * SEQLEN + cp * LC + (LC - 1)]);
  }
  #pragma unroll
  for (int j = 0; j < 16; ++j) {
    const unsigned v = (unsigned)f2bf(S[2 * j]) | ((unsigned)f2bf(S[2 * j + 1]) << 16);
    *(unsigned*)&Stile[p * 132 + n0 + 2 * j] = v;
  }
  __syncthreads();

  const ushort* rowbase = xbc + (size_t)(b * SEQLEN + c * LC) * CONV_DIM;
  const ushort* Cp = rowbase + (size_t)(wave * 16 + r16) * CONV_DIM + D_INNER + 128 + q * 8;
  f32x4 acc[4] = {};
  #pragma unroll
  for (int kk = 0; kk < 4; ++kk) {
    const bf16x8 a = *(const bf16x8*)(const void*)(Cp + kk * 32);
    #pragma unroll
    for (int j = 0; j < 4; ++j) {
      const bf16x8 bb = *(const bf16x8*)(const void*)(Stile + (j * 16 + r16) * 132 + kk * 32 + q * 8);
      acc[j] = __builtin_amdgcn_mfma_f32_16x16x32_bf16(a, bb, acc[j], 0, 0, 0);
    }
  }

  const float Dh = Dp[h];
  const ushort* Yp = Yi + (size_t)blk * 4096;
  float sc[4], ssq[4] = {0.f, 0.f, 0.f, 0.f};
  #pragma unroll
  for (int r = 0; r < 4; ++r)
    sc[r] = __expf(csum[(size_t)bh * SEQLEN + c * LC + wave * 16 + q * 4 + r]);
  #pragma unroll
  for (int j = 0; j < 4; ++j) {
    const int col = j * 16 + r16;
    #pragma unroll
    for (int r = 0; r < 4; ++r) {
      const int t = wave * 16 + q * 4 + r;
      const size_t row = (size_t)(b * SEQLEN + c * LC + t);
      const float xv = bf2f(xbc[row * CONV_DIM + h * HEADDIM + col]);
      const float yv = acc[j][r] * sc[r] + bf2f(Yp[t * 64 + col]) + Dh * xv;
      const float z  = bf2f(zx[row * D_IN_PROJ + h * HEADDIM + col]);
      const float yg = yv * (z / (1.f + __expf(-z)));
      yn[row * D_INNER + h * HEADDIM + col] = f2bf(yg);
      ssq[r] = fmaf(yg, yg, ssq[r]);
    }
  }
  #pragma unroll
  for (int o = 1; o < 16; o <<= 1) {
    #pragma unroll
    for (int r = 0; r < 4; ++r) ssq[r] += __shfl_xor(ssq[r], o);
  }
  if (r16 == 0) {
    #pragma unroll
    for (int r = 0; r < 4; ++r) {
      const int t = wave * 16 + q * 4 + r;
      unsafeAtomicAdd(&sumsq[b * SEQLEN + c * LC + t], ssq[r]);
    }
  }
}

// ---------------------------------------------------------------------------
extern "C" void kernel_launch(void* const* d_in, const int* in_sizes, int n_in,
                              void* d_out, int out_size, void* d_ws, size_t ws_size,
                              hipStream_t stream) {
  const float* u       = (const float*)d_in[0];
  const float* W_in    = (const float*)d_in[1];
  const float* conv_w  = (const float*)d_in[2];
  const float* conv_b  = (const float*)d_in[3];
  const float* dt_bias = (const float*)d_in[4];
  const float* A_log   = (const float*)d_in[5];
  const float* D_par   = (const float*)d_in[6];
  const float* norm_w  = (const float*)d_in[7];
  const float* W_out   = (const float*)d_in[8];
  float* out = (float*)d_out;

  char* ws = (char*)d_ws;
  // ws layout (bytes), 16B-aligned:
  //   zx_bf   bf16 [1024][4384]       8,978,432  @ 0
  //   xbc_bf  bf16 [1024][2304]       4,718,592  @ 8,978,432
  //   sumsq   fp32 [1024]                 4,096  @ 13,697,024
  //   yn      bf16 [1024][2048]       4,194,304  @ 13,701,120
  //   u_bf    bf16 [1024][1024]       2,097,152  @ 17,895,424   (dead after in_proj)
  //   Win_bf  bf16 [4384][1024]       8,978,432  @ 19,992,576   (dead after in_proj)
  //   Yi      bf16 [512][64][64]      4,194,304  @ 17,895,424   ALIAS u_bf+Win_bf
  //   Wout_bf bf16 [1024][2048]       4,194,304  @ 28,971,008
  //   dts     fp32 [64][512]            131,072  @ 33,165,312
  //   csum    fp32 [64][512]            131,072  @ 33,296,384
  //   dS      bf16 [512][128][64]     8,388,608  @ 33,427,456   (end 41,816,064)
  // in_proj reads Bt rows to 4480 -> 196,608 B past Win_bf into Wout_bf region
  // (finite bf16, written by cvt3z beforehand; results masked on store).
  ushort* zx      = (ushort*)ws;
  ushort* xbc     = (ushort*)(ws + 8978432);
  float*  sumsq   = (float*)(ws + 13697024);
  ushort* yn      = (ushort*)(ws + 13701120);
  ushort* u_bf    = (ushort*)(ws + 17895424);
  ushort* Win_bf  = (ushort*)(ws + 19992576);
  ushort* Yi      = (ushort*)(ws + 17895424);
  ushort* Wout_bf = (ushort*)(ws + 28971008);
  float*  dts     = (float*)(ws + 33165312);
  float*  csum    = (float*)(ws + 33296384);
  ushort* dS      = (ushort*)(ws + 33427456);

  const int n_u = M_TOKENS * D_MODEL, n_wi = D_IN_PROJ * D_MODEL, n_wo = D_MODEL * D_INNER;
  const int n_out = M_TOKENS * D_MODEL, n_ss = M_TOKENS;
  const int n_tot = n_u + n_wi + n_wo + n_out + n_ss;
  cvt3z<<<(n_tot + 2047) / 2048, 256, 0, stream>>>(
      u, u_bf, n_u, W_in, Win_bf, n_wi, W_out, Wout_bf, n_wo, norm_w,
      out, n_out, sumsq, n_ss);

  // in_proj: M=1024, N=4384 (grid padded to 4480), K=1024 — 560 blocks, BK=128
  gemm_tile<128, 64, 4><<<dim3(NPROJ_PAD / 64, M_TOKENS / 128), 256, 0, stream>>>(
      u_bf, Win_bf, zx, D_IN_PROJ, D_MODEL, D_IN_PROJ);
  // conv+silu (1152 blocks) and dt/csum (64 blocks) fused
  conv_dt<<<1152 + 64, 256, 0, stream>>>(zx, conv_w, conv_b, xbc,
                                         dt_bias, A_log, dts, csum);

  chunk_intra<<<BATCH * NHEADS * NCH, 256, 0, stream>>>(xbc, dts, csum, Yi, dS);
  chunk_inter<<<BATCH * NHEADS * NCH, 256, 0, stream>>>(xbc, dS, Yi, zx,
                                                        csum, D_par, yn, sumsq);

  // out_proj: M=1024, N=1024, K=2048 split 2x1024 — 512 blocks, rms in epilogue
  gemm_sk<<<dim3(D_MODEL / 64, M_TOKENS / 64, 2), 256, 0, stream>>>(
      yn, Wout_bf, out, sumsq, D_INNER / 2, D_INNER, D_MODEL);
}